// Round 12
// baseline (241.386 us; speedup 1.0000x reference)
//
#include <hip/hip_runtime.h>
#include <hip/hip_bf16.h>
#include <math.h>

// Problem constants (B=8, T=1024, C=32, F=256, D=128, K=512)
#define N_POS 8192      // B*T
#define D_DIM 128
#define K_DIM 512
#define C_DIM 32
#define F_DIM 256
#define NKT   4         // k-tiles (128 wide each)
#define GREC_COLS 8448  // 32*256 g_rec + 256 S
#define PB_BLOCKS 388   // phase-B participants: 256 sse + 128 grec + 4 S
#define XG_BLOCKS 256
#define GRID_ALL  768   // 256 XG + 512 NN (64pos x 128k tiles); 3 blocks/CU

// async global->LDS, 16B per lane, dest = wave-uniform base + lane*16
__device__ __forceinline__ void gll16(const float* g, float* l) {
    __builtin_amdgcn_global_load_lds(
        (const __attribute__((address_space(1))) void*)g,
        (__attribute__((address_space(3))) void*)l, 16, 0, 0);
}

// ---------------------------------------------------------------- reductions
__device__ __forceinline__ float block_reduce_256(float v) {
    __shared__ float sbuf[4];
    __syncthreads();
#pragma unroll
    for (int off = 32; off > 0; off >>= 1) v += __shfl_down(v, off);
    const int lane = threadIdx.x & 63;
    const int w    = threadIdx.x >> 6;
    if (lane == 0) sbuf[w] = v;
    __syncthreads();
    return (threadIdx.x == 0) ? (sbuf[0] + sbuf[1] + sbuf[2] + sbuf[3]) : 0.f;
}

// ===================== single kernel: phase A (R11's l1) + handshake + phase B
// R12: fuse l1+l2 WITHOUT cooperative launch (R4: coop fails graph capture).
// l1's tile-shape curve is mapped flat at ~40us (R9/R11 within 2%); remaining
// controllable time is l2's separate launch + gap + cold ramp. Resident-grid
// handshake: grid 768 = 3 blocks/CU exactly (25KB LDS -> 6/CU capacity,
// 12 waves/CU, VGPR<=85) => ALL blocks co-resident => spin cannot deadlock.
// Release: per-thread threadfence -> syncthreads -> tid0 atomicAdd(cnt[5]).
// Blocks >=388 exit; blocks <256 prefetch their 16 H values BEFORE spinning
// (independent of phase A); tid0 spins with s_sleep, then barrier + acquire
// fence -> phase B = l2 body (sse 0..255 / norm 256..387 / assemble, cnt[6]).
// XG blocks finish phase A earliest and take the sse role -> loaded & ready
// when the last NN block lands.
// Phase A NN identical to R11 (64pos x 128k, acc[4][8] split-k, GLL dbuf,
// lexicographic (dist,k) argmin -> exact first-min semantics).
__global__ __launch_bounds__(256, 6)
void fused_all(const float* __restrict__ H, const float* __restrict__ M,
               const float* __restrict__ Hdec, const float* __restrict__ W,
               const float* __restrict__ X, const float* __restrict__ w_d,
               float* __restrict__ MT, float* __restrict__ pd,
               int* __restrict__ pi, float* __restrict__ pp,
               float* __restrict__ accum, float* __restrict__ out) {
    __shared__ __align__(16) float smem[6144];   // 24KB
    const int tid = threadIdx.x;

    // ============================ PHASE A ==================================
    if (blockIdx.x >= XG_BLOCKS) {
        // ------------------------------- NN tile -------------------------------
        // hT dbuf [2][16][64] = smem[0..2047]; mT dbuf [2][16][128] = smem[2048..6143]
        float* rd = smem;                    // [16][64] alias (after final bar)
        int*   ri = (int*)(smem + 1024);     // [16][64] alias

        const int nb    = blockIdx.x - XG_BLOCKS;
        const int ptile = nb >> 2;           // 128 pos-tiles (64 wide)
        const int ktile = nb & 3;            // 4 k-tiles (128 wide)
        const int pos0  = ptile << 6;
        const int b     = pos0 >> 10;
        const int t0    = pos0 & 1023;
        const int k0    = ktile << 7;
        const float* Hb = H + (b << 17) + t0;

        const int wv = tid >> 6;             // wave id 0..3 (uniform per wave)
        const int p4 = (tid & 15) << 2;      // compute pos quad (0..60)
        const int q4 = (tid >> 4) << 2;      // compute k quad   (0..60), split-k

        // lane-linear staging sources (LDS float off == tid*4 per region/pass)
        const float* hsrc = Hb + (size_t)(tid >> 4) * 1024 + ((tid & 15) << 2);
        const float* msrc = M + (size_t)(tid >> 5) * K_DIM + k0 + ((tid & 31) << 2);
        float* hdstw = smem + (wv << 8);          // + sel*1024
        float* mdstw = smem + 2048 + (wv << 8);   // + sel*2048 + pass*1024

        float acc[4][8];
#pragma unroll
        for (int i = 0; i < 4; ++i)
#pragma unroll
            for (int j = 0; j < 8; ++j) acc[i][j] = 0.f;

        // stage chunk ch (16 d rows starting at ch*16) into buffer sel
        auto stage = [&](int ch, int sel) {
            const size_t dd = (size_t)ch << 4;
            gll16(hsrc + (dd << 10), hdstw + (sel << 10));
            gll16(msrc + dd * K_DIM,             mdstw + (sel << 11));
            gll16(msrc + (dd + 8) * K_DIM,       mdstw + (sel << 11) + 1024);
        };

        stage(0, 0);                         // prologue (drained by 1st barrier)

        for (int ch = 0; ch < 8; ++ch) {
            __syncthreads();   // drains vmcnt -> buf[ch&1] ready for ALL waves
            if (ch < 7) stage(ch + 1, (ch + 1) & 1);   // async into other buf

            const float* hc = smem + ((ch & 1) << 10);
            const float* mc = smem + 2048 + ((ch & 1) << 11);
#pragma unroll 4
            for (int d = 0; d < 16; ++d) {
                const float4 ha = *(const float4*)(hc + (d << 6) + p4);
                const float4 m0 = *(const float4*)(mc + (d << 7) + q4);
                const float4 m1 = *(const float4*)(mc + (d << 7) + 64 + q4);
                const float hh[4] = {ha.x, ha.y, ha.z, ha.w};
                const float mm[8] = {m0.x, m0.y, m0.z, m0.w,
                                     m1.x, m1.y, m1.z, m1.w};
#pragma unroll
                for (int i = 0; i < 4; ++i)
#pragma unroll
                    for (int j = 0; j < 8; ++j) {
                        const float dv = hh[i] - mm[j];
                        asm("v_add_f32 %0, %0, abs(%1)"
                            : "+v"(acc[i][j]) : "v"(dv));
                    }
            }
        }

        __syncthreads();   // all reads of smem done before aliasing as rd/ri

        // per-thread argmin over its 8 ks (j ascending = k ascending; strict <)
#pragma unroll
        for (int i = 0; i < 4; ++i) {
            const int pl = p4 + i;           // local pos 0..63
            float bd = acc[i][0];
            int   bj = 0;
#pragma unroll
            for (int j = 1; j < 8; ++j)
                if (acc[i][j] < bd) { bd = acc[i][j]; bj = j; }
            const int bk = k0 + ((bj < 4) ? (q4 + bj) : (64 + q4 + bj - 4));
            rd[(tid >> 4) * 64 + pl] = bd;
            ri[(tid >> 4) * 64 + pl] = bk;
        }
        __syncthreads();

        // cross-thread merge: 16 k-groups, lexicographic (dist, k)
        if (tid < 64) {
            float bd = rd[tid];
            int   bi = ri[tid];
#pragma unroll
            for (int q = 1; q < 16; ++q) {
                const float d = rd[q * 64 + tid];
                const int   k = ri[q * 64 + tid];
                if (d < bd || (d == bd && k < bi)) { bd = d; bi = k; }
            }
            pd[ktile * N_POS + pos0 + tid] = bd;
            pi[ktile * N_POS + pos0 + tid] = bi;
        }
    } else {
        // --------------------- XHAT + E(LDS) + GREC partials -------------------
        float* El = smem;                    // [32][32]
        const int xb  = blockIdx.x;          // 0..255
        const int bt0 = xb << 5;

        // first 64 xg blocks transpose one 2-d x 512-k slab of M into MT
        if (xb < 64) {
            const int d0 = xb << 1;          // 2 d-rows per block, 512 k each
            const int d  = d0 + (tid >> 7);
            const int k  = (tid & 127) << 2;
#pragma unroll
            for (int j = 0; j < 4; ++j)
                MT[(size_t)(k + j) * D_DIM + d] = M[(size_t)d * K_DIM + k + j];
        }

        const int c  = tid & 31;
        const int rg = tid >> 5;
        const int r0 = bt0 + rg, r1 = r0 + 8, r2 = r0 + 16, r3 = r0 + 24;

        // W row c read straight from global: 32KB total, L1/L2-resident.
        const float* Wc = W + (size_t)c * F_DIM;

        float a0 = 0.f, a1 = 0.f, a2 = 0.f, a3 = 0.f;
#pragma unroll 4
        for (int f0 = 0; f0 < F_DIM; f0 += 4) {
            const float4 w4 = *(const float4*)(Wc + f0);
            const float4 h0 = *(const float4*)(Hdec + (size_t)r0 * F_DIM + f0);
            const float4 h1 = *(const float4*)(Hdec + (size_t)r1 * F_DIM + f0);
            const float4 h2 = *(const float4*)(Hdec + (size_t)r2 * F_DIM + f0);
            const float4 h3 = *(const float4*)(Hdec + (size_t)r3 * F_DIM + f0);
            a0 += h0.x * w4.x + h0.y * w4.y + h0.z * w4.z + h0.w * w4.w;
            a1 += h1.x * w4.x + h1.y * w4.y + h1.z * w4.z + h1.w * w4.w;
            a2 += h2.x * w4.x + h2.y * w4.y + h2.z * w4.z + h2.w * w4.w;
            a3 += h3.x * w4.x + h3.y * w4.y + h3.z * w4.z + h3.w * w4.w;
        }

        const float wd = w_d[c];
        const float e0 = a0 - X[(size_t)r0 * C_DIM + c];
        const float e1 = a1 - X[(size_t)r1 * C_DIM + c];
        const float e2 = a2 - X[(size_t)r2 * C_DIM + c];
        const float e3 = a3 - X[(size_t)r3 * C_DIM + c];
        El[(rg)      * 32 + c] = e0;
        El[(rg + 8)  * 32 + c] = e1;
        El[(rg + 16) * 32 + c] = e2;
        El[(rg + 24) * 32 + c] = e3;
        const float sse = e0 * e0 + e1 * e1 + e2 * e2 + e3 * e3;
        const float dp  = (a0 + a1 + a2 + a3) * wd;
        const float rA = block_reduce_256(sse);
        if (tid == 0) atomicAdd(accum + 0, rA);
        const float rB = block_reduce_256(dp);
        if (tid == 0) atomicAdd(accum + 1, rB);
        __syncthreads();   // El fully visible

        // grec: thread = f; E rows via LDS float4 broadcast; 2-deep prefetch.
        const int f = tid;
        const float* hp = Hdec + (size_t)bt0 * F_DIM + f;
        float gacc[C_DIM];
#pragma unroll
        for (int cc = 0; cc < C_DIM; ++cc) gacc[cc] = 0.f;
        float sf = 0.f;
        float hd0 = hp[0];
        float hd1 = hp[F_DIM];
#pragma unroll 1
        for (int i = 0; i < 30; ++i) {
            const float hdn = hp[(size_t)(i + 2) * F_DIM];
            sf += hd0;
#pragma unroll
            for (int c4 = 0; c4 < 8; ++c4) {
                const float4 e4 = *(const float4*)(El + i * 32 + c4 * 4);
                gacc[c4 * 4 + 0] += e4.x * hd0;
                gacc[c4 * 4 + 1] += e4.y * hd0;
                gacc[c4 * 4 + 2] += e4.z * hd0;
                gacc[c4 * 4 + 3] += e4.w * hd0;
            }
            hd0 = hd1; hd1 = hdn;
        }
#pragma unroll
        for (int i = 30; i < 32; ++i) {
            sf += hd0;
#pragma unroll
            for (int c4 = 0; c4 < 8; ++c4) {
                const float4 e4 = *(const float4*)(El + i * 32 + c4 * 4);
                gacc[c4 * 4 + 0] += e4.x * hd0;
                gacc[c4 * 4 + 1] += e4.y * hd0;
                gacc[c4 * 4 + 2] += e4.z * hd0;
                gacc[c4 * 4 + 3] += e4.w * hd0;
            }
            hd0 = hd1;
        }
        float* o = pp + (size_t)xb * GREC_COLS;
#pragma unroll
        for (int cc = 0; cc < C_DIM; ++cc) o[cc * F_DIM + f] = gacc[cc];
        o[8192 + f] = sf;
    }

    // ================== phase-A release + resident-grid handshake ==========
    __threadfence();                 // every thread releases its global writes
    __syncthreads();
    if (tid == 0) atomicAdd((unsigned int*)(accum + 5), 1u);
    if (blockIdx.x >= PB_BLOCKS) return;     // 388..767: done

    // sse blocks (<256): prefetch H (independent of phase A) before spinning
    const int pbx = blockIdx.x;
    const int bx = pbx & 31, by = pbx >> 5;
    const int pos = bx * 256 + tid;
    const int d0 = by * 16;
    float hv[16];
    if (pbx < 256) {
        const float* Hb2 = H + ((pos >> 10) << 17) + (pos & 1023) + (d0 << 10);
#pragma unroll
        for (int j = 0; j < 16; ++j) hv[j] = Hb2[j << 10];
    }

    if (tid == 0) {
        while (__hip_atomic_load((unsigned int*)(accum + 5),
                                 __ATOMIC_RELAXED,
                                 __HIP_MEMORY_SCOPE_AGENT) < GRID_ALL)
            __builtin_amdgcn_s_sleep(2);
    }
    __syncthreads();
    __threadfence();                 // acquire: phase-A writes now visible

    // ============================ PHASE B ==================================
    if (pbx < 256) {
        // ---------------- chunk-merge + memory-loss SSE ----------------
        float bd = INFINITY;
        int   bi = 0x7fffffff;
#pragma unroll
        for (int p = 0; p < NKT; ++p) {
            const float d = pd[p * N_POS + pos];
            const int   k = pi[p * N_POS + pos];
            if (d < bd || (d == bd && k < bi)) { bd = d; bi = k; }
        }

        const float* z  = MT + (size_t)bi * D_DIM + d0;
        const float4 z0 = *(const float4*)(z);
        const float4 z1 = *(const float4*)(z + 4);
        const float4 z2 = *(const float4*)(z + 8);
        const float4 z3 = *(const float4*)(z + 12);
        float s0 = 0.f, s1 = 0.f, s2 = 0.f, s3 = 0.f;
        float e;
        e = hv[0]  - z0.x; s0 += e * e;
        e = hv[1]  - z0.y; s1 += e * e;
        e = hv[2]  - z0.z; s2 += e * e;
        e = hv[3]  - z0.w; s3 += e * e;
        e = hv[4]  - z1.x; s0 += e * e;
        e = hv[5]  - z1.y; s1 += e * e;
        e = hv[6]  - z1.z; s2 += e * e;
        e = hv[7]  - z1.w; s3 += e * e;
        e = hv[8]  - z2.x; s0 += e * e;
        e = hv[9]  - z2.y; s1 += e * e;
        e = hv[10] - z2.z; s2 += e * e;
        e = hv[11] - z2.w; s3 += e * e;
        e = hv[12] - z3.x; s0 += e * e;
        e = hv[13] - z3.y; s1 += e * e;
        e = hv[14] - z3.z; s2 += e * e;
        e = hv[15] - z3.w; s3 += e * e;
        const float r = block_reduce_256((s0 + s1) + (s2 + s3));
        if (tid == 0) atomicAdd(accum + 2, r);
    } else {
        // ---------------- norm reductions over pp ----------------
        const int g = pbx - 256;                       // 0..131
        const int col = (g < 128) ? (g * 64 + (tid & 63))
                                  : (8192 + (g - 128) * 64 + (tid & 63));
        const int pc  = tid >> 6;                      // 0..3
        const float* base = pp + (size_t)(pc * 64) * GREC_COLS + col;
        float s = 0.f;
#pragma unroll 8
        for (int p = 0; p < 64; ++p) s += base[(size_t)p * GREC_COLS];
        __shared__ float red[4][64];
        red[pc][tid & 63] = s;
        __syncthreads();
        if (tid < 64) {
            const float tot = red[0][tid] + red[1][tid] +
                              red[2][tid] + red[3][tid];
            float v = tot * tot;
#pragma unroll
            for (int off = 32; off > 0; off >>= 1) v += __shfl_down(v, off);
            if (tid == 0)
                atomicAdd(accum + ((g >= 128) ? 4 : 3), v);
        }
    }

    // ---- last phase-B block to finish assembles the scalar ----
    __shared__ int is_last;
    if (tid == 0) {
        __threadfence();
        unsigned int* cnt = (unsigned int*)(accum + 6);
        is_last = (atomicAdd(cnt, 1u) == PB_BLOCKS - 1);
    }
    __syncthreads();
    if (is_last && tid < 64) {
        float wd2 = (tid < C_DIM) ? w_d[tid] * w_d[tid] : 0.f;
#pragma unroll
        for (int off = 32; off > 0; off >>= 1) wd2 += __shfl_down(wd2, off);
        if (tid == 0) {
            __threadfence();
            const float sse_rec = atomicAdd(accum + 0, 0.f);
            const float dsum    = atomicAdd(accum + 1, 0.f);
            const float sse_mem = atomicAdd(accum + 2, 0.f);
            const float g2      = atomicAdd(accum + 3, 0.f);
            const float s2      = atomicAdd(accum + 4, 0.f);
            const float loss_rec = sse_rec / 262144.f;         // /(B*T*C)
            const float loss_d   = -dsum / 8192.f;             // -mean over B*T
            const float loss_m   = 2.f * sse_mem / 1048576.f;  // 2*SSE/(B*D*T)
            const float ngrec    = (2.f / 262144.f) * sqrtf(g2);
            const float ngd      = sqrtf(wd2 * s2) / 8192.f;
            const float lmbda    = ngrec / (ngd + 1e-6f);
            out[0] = loss_rec + loss_m + lmbda * loss_d;       // ALPHA = 1
        }
    }
}

// ---------------------------------------------------------------- launcher
extern "C" void kernel_launch(void* const* d_in, const int* in_sizes, int n_in,
                              void* d_out, int out_size, void* d_ws, size_t ws_size,
                              hipStream_t stream) {
    const float* X    = (const float*)d_in[0];   // [8,1024,32]
    const float* H    = (const float*)d_in[1];   // [8,128,1024]
    const float* M    = (const float*)d_in[2];   // [128,512]
    const float* Hdec = (const float*)d_in[3];   // [8,1024,256]
    const float* W    = (const float*)d_in[4];   // [32,256]
    const float* w_d  = (const float*)d_in[5];   // [32]

    float* ws    = (float*)d_ws;
    float* MT    = ws;                      // 65536 floats
    float* accum = ws + 65536;              // 16 (counters at [5],[6])
    float* pd    = ws + 65552;              // 4*8192 = 32768
    int*   pi    = (int*)(ws + 98320);      // 32768
    float* pp    = ws + 131088;             // 256*8448 = 2162688  (~9.2 MB total)

    hipMemsetAsync(accum, 0, 16 * sizeof(float), stream);
    fused_all<<<GRID_ALL, 256, 0, stream>>>(H, M, Hdec, W, X, w_d,
                                            MT, pd, pi, pp, accum,
                                            (float*)d_out);
}

// Round 13
// 167.552 us; speedup vs baseline: 1.4407x; 1.4407x over previous
//
#include <hip/hip_runtime.h>
#include <hip/hip_bf16.h>
#include <math.h>

// Problem constants (B=8, T=1024, C=32, F=256, D=128, K=512)
#define N_POS 8192      // B*T
#define D_DIM 128
#define K_DIM 512
#define C_DIM 32
#define F_DIM 256
#define NKT   4         // k-tiles (128 wide each)
#define GREC_COLS 8448  // 32*256 g_rec + 256 S
#define L2_BLOCKS 256   // merge+SSE only (norm reduce moved into l1 XG)
#define XG_BLOCKS 256
#define GRID_L1   768   // 256 XG + 512 NN (64pos x 128k tiles)

// async global->LDS, 16B per lane, dest = wave-uniform base + lane*16
__device__ __forceinline__ void gll16(const float* g, float* l) {
    __builtin_amdgcn_global_load_lds(
        (const __attribute__((address_space(1))) void*)g,
        (__attribute__((address_space(3))) void*)l, 16, 0, 0);
}

// ---------------------------------------------------------------- reductions
__device__ __forceinline__ float block_reduce_256(float v) {
    __shared__ float sbuf[4];
    __syncthreads();
#pragma unroll
    for (int off = 32; off > 0; off >>= 1) v += __shfl_down(v, off);
    const int lane = threadIdx.x & 63;
    const int w    = threadIdx.x >> 6;
    if (lane == 0) sbuf[w] = v;
    __syncthreads();
    return (threadIdx.x == 0) ? (sbuf[0] + sbuf[1] + sbuf[2] + sbuf[3]) : 0.f;
}

// =====================  L1: XG (blocks 0..255) + NN (256..767)  =============
// R13: R11 (best, 121.9us) + XG-only handshake. R12 post-mortem: an all-grid
// spin serialized the dispatch into two passes (residency NOT guaranteed at
// 3 blocks/CU). Safe variant: handshake among the 256 XG blocks ONLY — they
// are blockIdx 0..255, first-dispatched, <=1/CU -> provably all co-resident,
// and they finish phase A within ~2us of each other. After writing pp, XG
// blocks release via accum[5]; blocks 0..131 spin (s_sleep), then run the pp
// norm reductions (g_rec 128 + S 4) entirely in the shadow of the ~30us NN
// bulk. fused_l2 shrinks to 256 merge+SSE blocks + assemble (target 256).
// NN identical to R11 (64pos x 128k, acc[4][8] split-k, GLL dbuf, 2-way-free
// LDS layout, lexicographic (dist,k) argmin -> exact first-min semantics).
__global__ __launch_bounds__(256, 6)
void fused_l1(const float* __restrict__ H, const float* __restrict__ M,
              const float* __restrict__ Hdec, const float* __restrict__ W,
              const float* __restrict__ X, const float* __restrict__ w_d,
              float* __restrict__ MT, float* __restrict__ pd,
              int* __restrict__ pi, float* __restrict__ pp,
              float* __restrict__ accum) {
    __shared__ __align__(16) float smem[6144];   // 24KB
    const int tid = threadIdx.x;

    if (blockIdx.x >= XG_BLOCKS) {
        // ------------------------------- NN tile -------------------------------
        // hT dbuf [2][16][64] = smem[0..2047]; mT dbuf [2][16][128] = smem[2048..6143]
        float* rd = smem;                    // [16][64] alias (after final bar)
        int*   ri = (int*)(smem + 1024);     // [16][64] alias

        const int nb    = blockIdx.x - XG_BLOCKS;
        const int ptile = nb >> 2;           // 128 pos-tiles (64 wide)
        const int ktile = nb & 3;            // 4 k-tiles (128 wide)
        const int pos0  = ptile << 6;
        const int b     = pos0 >> 10;
        const int t0    = pos0 & 1023;
        const int k0    = ktile << 7;
        const float* Hb = H + (b << 17) + t0;

        const int wv = tid >> 6;             // wave id 0..3 (uniform per wave)
        const int p4 = (tid & 15) << 2;      // compute pos quad (0..60)
        const int q4 = (tid >> 4) << 2;      // compute k quad   (0..60), split-k

        // lane-linear staging sources (LDS float off == tid*4 per region/pass)
        const float* hsrc = Hb + (size_t)(tid >> 4) * 1024 + ((tid & 15) << 2);
        const float* msrc = M + (size_t)(tid >> 5) * K_DIM + k0 + ((tid & 31) << 2);
        float* hdstw = smem + (wv << 8);          // + sel*1024
        float* mdstw = smem + 2048 + (wv << 8);   // + sel*2048 + pass*1024

        float acc[4][8];
#pragma unroll
        for (int i = 0; i < 4; ++i)
#pragma unroll
            for (int j = 0; j < 8; ++j) acc[i][j] = 0.f;

        // stage chunk ch (16 d rows starting at ch*16) into buffer sel
        auto stage = [&](int ch, int sel) {
            const size_t dd = (size_t)ch << 4;
            gll16(hsrc + (dd << 10), hdstw + (sel << 10));
            gll16(msrc + dd * K_DIM,             mdstw + (sel << 11));
            gll16(msrc + (dd + 8) * K_DIM,       mdstw + (sel << 11) + 1024);
        };

        stage(0, 0);                         // prologue (drained by 1st barrier)

        for (int ch = 0; ch < 8; ++ch) {
            __syncthreads();   // drains vmcnt -> buf[ch&1] ready for ALL waves
            if (ch < 7) stage(ch + 1, (ch + 1) & 1);   // async into other buf

            const float* hc = smem + ((ch & 1) << 10);
            const float* mc = smem + 2048 + ((ch & 1) << 11);
#pragma unroll 4
            for (int d = 0; d < 16; ++d) {
                const float4 ha = *(const float4*)(hc + (d << 6) + p4);
                const float4 m0 = *(const float4*)(mc + (d << 7) + q4);
                const float4 m1 = *(const float4*)(mc + (d << 7) + 64 + q4);
                const float hh[4] = {ha.x, ha.y, ha.z, ha.w};
                const float mm[8] = {m0.x, m0.y, m0.z, m0.w,
                                     m1.x, m1.y, m1.z, m1.w};
#pragma unroll
                for (int i = 0; i < 4; ++i)
#pragma unroll
                    for (int j = 0; j < 8; ++j) {
                        const float dv = hh[i] - mm[j];
                        asm("v_add_f32 %0, %0, abs(%1)"
                            : "+v"(acc[i][j]) : "v"(dv));
                    }
            }
        }

        __syncthreads();   // all reads of smem done before aliasing as rd/ri

        // per-thread argmin over its 8 ks (j ascending = k ascending; strict <)
#pragma unroll
        for (int i = 0; i < 4; ++i) {
            const int pl = p4 + i;           // local pos 0..63
            float bd = acc[i][0];
            int   bj = 0;
#pragma unroll
            for (int j = 1; j < 8; ++j)
                if (acc[i][j] < bd) { bd = acc[i][j]; bj = j; }
            const int bk = k0 + ((bj < 4) ? (q4 + bj) : (64 + q4 + bj - 4));
            rd[(tid >> 4) * 64 + pl] = bd;
            ri[(tid >> 4) * 64 + pl] = bk;
        }
        __syncthreads();

        // cross-thread merge: 16 k-groups, lexicographic (dist, k)
        if (tid < 64) {
            float bd = rd[tid];
            int   bi = ri[tid];
#pragma unroll
            for (int q = 1; q < 16; ++q) {
                const float d = rd[q * 64 + tid];
                const int   k = ri[q * 64 + tid];
                if (d < bd || (d == bd && k < bi)) { bd = d; bi = k; }
            }
            pd[ktile * N_POS + pos0 + tid] = bd;
            pi[ktile * N_POS + pos0 + tid] = bi;
        }
    } else {
        // --------------------- XHAT + E(LDS) + GREC partials -------------------
        float* El = smem;                    // [32][32]
        const int xb  = blockIdx.x;          // 0..255
        const int bt0 = xb << 5;

        // first 64 xg blocks transpose one 2-d x 512-k slab of M into MT
        if (xb < 64) {
            const int d0 = xb << 1;          // 2 d-rows per block, 512 k each
            const int d  = d0 + (tid >> 7);
            const int k  = (tid & 127) << 2;
#pragma unroll
            for (int j = 0; j < 4; ++j)
                MT[(size_t)(k + j) * D_DIM + d] = M[(size_t)d * K_DIM + k + j];
        }

        const int c  = tid & 31;
        const int rg = tid >> 5;
        const int r0 = bt0 + rg, r1 = r0 + 8, r2 = r0 + 16, r3 = r0 + 24;

        // W row c read straight from global: 32KB total, L1/L2-resident.
        const float* Wc = W + (size_t)c * F_DIM;

        float a0 = 0.f, a1 = 0.f, a2 = 0.f, a3 = 0.f;
#pragma unroll 4
        for (int f0 = 0; f0 < F_DIM; f0 += 4) {
            const float4 w4 = *(const float4*)(Wc + f0);
            const float4 h0 = *(const float4*)(Hdec + (size_t)r0 * F_DIM + f0);
            const float4 h1 = *(const float4*)(Hdec + (size_t)r1 * F_DIM + f0);
            const float4 h2 = *(const float4*)(Hdec + (size_t)r2 * F_DIM + f0);
            const float4 h3 = *(const float4*)(Hdec + (size_t)r3 * F_DIM + f0);
            a0 += h0.x * w4.x + h0.y * w4.y + h0.z * w4.z + h0.w * w4.w;
            a1 += h1.x * w4.x + h1.y * w4.y + h1.z * w4.z + h1.w * w4.w;
            a2 += h2.x * w4.x + h2.y * w4.y + h2.z * w4.z + h2.w * w4.w;
            a3 += h3.x * w4.x + h3.y * w4.y + h3.z * w4.z + h3.w * w4.w;
        }

        const float wd = w_d[c];
        const float e0 = a0 - X[(size_t)r0 * C_DIM + c];
        const float e1 = a1 - X[(size_t)r1 * C_DIM + c];
        const float e2 = a2 - X[(size_t)r2 * C_DIM + c];
        const float e3 = a3 - X[(size_t)r3 * C_DIM + c];
        El[(rg)      * 32 + c] = e0;
        El[(rg + 8)  * 32 + c] = e1;
        El[(rg + 16) * 32 + c] = e2;
        El[(rg + 24) * 32 + c] = e3;
        const float sse = e0 * e0 + e1 * e1 + e2 * e2 + e3 * e3;
        const float dp  = (a0 + a1 + a2 + a3) * wd;
        const float rA = block_reduce_256(sse);
        if (tid == 0) atomicAdd(accum + 0, rA);
        const float rB = block_reduce_256(dp);
        if (tid == 0) atomicAdd(accum + 1, rB);
        __syncthreads();   // El fully visible

        // grec: thread = f; E rows via LDS float4 broadcast; 2-deep prefetch.
        const int f = tid;
        const float* hp = Hdec + (size_t)bt0 * F_DIM + f;
        float gacc[C_DIM];
#pragma unroll
        for (int cc = 0; cc < C_DIM; ++cc) gacc[cc] = 0.f;
        float sf = 0.f;
        float hd0 = hp[0];
        float hd1 = hp[F_DIM];
#pragma unroll 1
        for (int i = 0; i < 30; ++i) {
            const float hdn = hp[(size_t)(i + 2) * F_DIM];
            sf += hd0;
#pragma unroll
            for (int c4 = 0; c4 < 8; ++c4) {
                const float4 e4 = *(const float4*)(El + i * 32 + c4 * 4);
                gacc[c4 * 4 + 0] += e4.x * hd0;
                gacc[c4 * 4 + 1] += e4.y * hd0;
                gacc[c4 * 4 + 2] += e4.z * hd0;
                gacc[c4 * 4 + 3] += e4.w * hd0;
            }
            hd0 = hd1; hd1 = hdn;
        }
#pragma unroll
        for (int i = 30; i < 32; ++i) {
            sf += hd0;
#pragma unroll
            for (int c4 = 0; c4 < 8; ++c4) {
                const float4 e4 = *(const float4*)(El + i * 32 + c4 * 4);
                gacc[c4 * 4 + 0] += e4.x * hd0;
                gacc[c4 * 4 + 1] += e4.y * hd0;
                gacc[c4 * 4 + 2] += e4.z * hd0;
                gacc[c4 * 4 + 3] += e4.w * hd0;
            }
            hd0 = hd1;
        }
        float* o = pp + (size_t)xb * GREC_COLS;
#pragma unroll
        for (int cc = 0; cc < C_DIM; ++cc) o[cc * F_DIM + f] = gacc[cc];
        o[8192 + f] = sf;

        // ---------- XG-only handshake: pp complete -> norm reductions ----------
        // Participants: blocks 0..255, first-dispatched, <=1/CU -> all
        // co-resident; spin cannot deadlock and lasts ~us (XG blocks finish
        // phase A nearly simultaneously). Runs in the shadow of the NN bulk.
        __threadfence();             // release this block's pp writes
        __syncthreads();
        if (tid == 0) atomicAdd((unsigned int*)(accum + 5), 1u);

        if (xb < 132) {
            if (tid == 0) {
                while (__hip_atomic_load((unsigned int*)(accum + 5),
                                         __ATOMIC_RELAXED,
                                         __HIP_MEMORY_SCOPE_AGENT) < XG_BLOCKS)
                    __builtin_amdgcn_s_sleep(2);
            }
            __syncthreads();
            __threadfence();         // acquire: all pp writes visible

            const int g = xb;                          // 0..131
            const int col = (g < 128) ? (g * 64 + (tid & 63))
                                      : (8192 + (g - 128) * 64 + (tid & 63));
            const int pc  = tid >> 6;                  // 0..3
            const float* base = pp + (size_t)(pc * 64) * GREC_COLS + col;
            float s = 0.f;
#pragma unroll 8
            for (int p = 0; p < 64; ++p) s += base[(size_t)p * GREC_COLS];
            float* red = smem + 4096;                  // [4][64], free region
            red[pc * 64 + (tid & 63)] = s;
            __syncthreads();
            if (tid < 64) {
                const float tot = red[0 * 64 + tid] + red[1 * 64 + tid] +
                                  red[2 * 64 + tid] + red[3 * 64 + tid];
                float v = tot * tot;
#pragma unroll
                for (int off = 32; off > 0; off >>= 1) v += __shfl_down(v, off);
                if (tid == 0)
                    atomicAdd(accum + ((g >= 128) ? 4 : 3), v);
            }
        }
    }
}

// ============ L2: merge+SSE (0..255) + assemble (last block) ================
__global__ __launch_bounds__(256)
void fused_l2(const float* __restrict__ H, const float* __restrict__ MT,
              const float* __restrict__ pd, const int* __restrict__ pi,
              const float* __restrict__ w_d,
              float* __restrict__ accum, float* __restrict__ out) {
    const int tid = threadIdx.x;
    // ---------------- chunk-merge + memory-loss SSE ----------------
    const int bx = blockIdx.x & 31;      // pos-block
    const int by = blockIdx.x >> 5;      // d-slice 0..7
    const int pos = bx * 256 + tid;
    const int b = pos >> 10;
    const int t = pos & 1023;

    // H loads are independent of the merge -> issue them FIRST (MLP)
    const int d0 = by * 16;
    const float* Hb = H + (b << 17) + t + (d0 << 10);
    float hv[16];
#pragma unroll
    for (int j = 0; j < 16; ++j) hv[j] = Hb[j << 10];

    float bd = INFINITY;
    int   bi = 0x7fffffff;
#pragma unroll
    for (int p = 0; p < NKT; ++p) {
        const float d = pd[p * N_POS + pos];
        const int   k = pi[p * N_POS + pos];
        if (d < bd || (d == bd && k < bi)) { bd = d; bi = k; }
    }

    const float* z  = MT + (size_t)bi * D_DIM + d0;
    const float4 z0 = *(const float4*)(z);
    const float4 z1 = *(const float4*)(z + 4);
    const float4 z2 = *(const float4*)(z + 8);
    const float4 z3 = *(const float4*)(z + 12);
    float s0 = 0.f, s1 = 0.f, s2 = 0.f, s3 = 0.f;
    float e;
    e = hv[0]  - z0.x; s0 += e * e;
    e = hv[1]  - z0.y; s1 += e * e;
    e = hv[2]  - z0.z; s2 += e * e;
    e = hv[3]  - z0.w; s3 += e * e;
    e = hv[4]  - z1.x; s0 += e * e;
    e = hv[5]  - z1.y; s1 += e * e;
    e = hv[6]  - z1.z; s2 += e * e;
    e = hv[7]  - z1.w; s3 += e * e;
    e = hv[8]  - z2.x; s0 += e * e;
    e = hv[9]  - z2.y; s1 += e * e;
    e = hv[10] - z2.z; s2 += e * e;
    e = hv[11] - z2.w; s3 += e * e;
    e = hv[12] - z3.x; s0 += e * e;
    e = hv[13] - z3.y; s1 += e * e;
    e = hv[14] - z3.z; s2 += e * e;
    e = hv[15] - z3.w; s3 += e * e;
    const float r = block_reduce_256((s0 + s1) + (s2 + s3));
    if (tid == 0) atomicAdd(accum + 2, r);

    // ---- last block to finish assembles the scalar ----
    __shared__ int is_last;
    if (tid == 0) {
        __threadfence();
        unsigned int* cnt = (unsigned int*)(accum + 6);
        is_last = (atomicAdd(cnt, 1u) == L2_BLOCKS - 1);
    }
    __syncthreads();
    if (is_last && tid < 64) {
        float wd2 = (tid < C_DIM) ? w_d[tid] * w_d[tid] : 0.f;
#pragma unroll
        for (int off = 32; off > 0; off >>= 1) wd2 += __shfl_down(wd2, off);
        if (tid == 0) {
            __threadfence();
            const float sse_rec = atomicAdd(accum + 0, 0.f);
            const float dsum    = atomicAdd(accum + 1, 0.f);
            const float sse_mem = atomicAdd(accum + 2, 0.f);
            const float g2      = atomicAdd(accum + 3, 0.f);
            const float s2      = atomicAdd(accum + 4, 0.f);
            const float loss_rec = sse_rec / 262144.f;         // /(B*T*C)
            const float loss_d   = -dsum / 8192.f;             // -mean over B*T
            const float loss_m   = 2.f * sse_mem / 1048576.f;  // 2*SSE/(B*D*T)
            const float ngrec    = (2.f / 262144.f) * sqrtf(g2);
            const float ngd      = sqrtf(wd2 * s2) / 8192.f;
            const float lmbda    = ngrec / (ngd + 1e-6f);
            out[0] = loss_rec + loss_m + lmbda * loss_d;       // ALPHA = 1
        }
    }
}

// ---------------------------------------------------------------- launcher
extern "C" void kernel_launch(void* const* d_in, const int* in_sizes, int n_in,
                              void* d_out, int out_size, void* d_ws, size_t ws_size,
                              hipStream_t stream) {
    const float* X    = (const float*)d_in[0];   // [8,1024,32]
    const float* H    = (const float*)d_in[1];   // [8,128,1024]
    const float* M    = (const float*)d_in[2];   // [128,512]
    const float* Hdec = (const float*)d_in[3];   // [8,1024,256]
    const float* W    = (const float*)d_in[4];   // [32,256]
    const float* w_d  = (const float*)d_in[5];   // [32]

    float* ws    = (float*)d_ws;
    float* MT    = ws;                      // 65536 floats
    float* accum = ws + 65536;              // 16 (counters at [5],[6])
    float* pd    = ws + 65552;              // 4*8192 = 32768
    int*   pi    = (int*)(ws + 98320);      // 32768
    float* pp    = ws + 131088;             // 256*8448 = 2162688  (~9.2 MB total)

    hipMemsetAsync(accum, 0, 16 * sizeof(float), stream);
    fused_l1<<<GRID_L1,   256, 0, stream>>>(H, M, Hdec, W, X, w_d,
                                            MT, pd, pi, pp, accum);
    fused_l2<<<L2_BLOCKS, 256, 0, stream>>>(H, MT, pd, pi, w_d,
                                            accum, (float*)d_out);
}

// Round 14
// 120.986 us; speedup vs baseline: 1.9952x; 1.3849x over previous
//
#include <hip/hip_runtime.h>
#include <hip/hip_bf16.h>
#include <math.h>

// Problem constants (B=8, T=1024, C=32, F=256, D=128, K=512)
#define N_POS 8192      // B*T
#define D_DIM 128
#define K_DIM 512
#define C_DIM 32
#define F_DIM 256
#define NKT   4         // k-tiles (128 wide each)
#define GREC_COLS 8448  // 32*256 g_rec + 256 S
#define L2_BLOCKS 388   // 256 sse + 128 grec + 4 S
#define XG_BLOCKS 256
#define GRID_L1   768   // 256 XG + 512 NN (64pos x 128k tiles)

// async global->LDS, 16B per lane, dest = wave-uniform base + lane*16
__device__ __forceinline__ void gll16(const float* g, float* l) {
    __builtin_amdgcn_global_load_lds(
        (const __attribute__((address_space(1))) void*)g,
        (__attribute__((address_space(3))) void*)l, 16, 0, 0);
}

// ---------------------------------------------------------------- reductions
__device__ __forceinline__ float block_reduce_256(float v) {
    __shared__ float sbuf[4];
    __syncthreads();
#pragma unroll
    for (int off = 32; off > 0; off >>= 1) v += __shfl_down(v, off);
    const int lane = threadIdx.x & 63;
    const int w    = threadIdx.x >> 6;
    if (lane == 0) sbuf[w] = v;
    __syncthreads();
    return (threadIdx.x == 0) ? (sbuf[0] + sbuf[1] + sbuf[2] + sbuf[3]) : 0.f;
}

// =====================  L1: XG (blocks 0..255) + NN (256..767)  =============
// R14 = R11 revert (measured best, 121.9us). R12 (all-grid spin) and R13
// (XG-subset spin) both regressed: spin slot-occupancy cost >> the ~8us of
// launch/ramp it could save; intra-kernel sync is refuted on this harness.
// l1 ledger: real VALU ~15us (2-inst/el floor: v_sub + v_add-abs), LDS ~15us
// (4x8 split-k = 1.5B/acc, 2-way-conflict-free), staging latency hidden by
// GLL double-buffer (16-d chunks, 3 GLL/chunk, 24KB LDS, 1 barrier/chunk).
// Tile-shape curve mapped flat at ~40-42us (R9 4x4 / R11 4x8 / R10 8x8).
// Argmin lexicographic (dist, k): j ascending = k ascending within thread
// (q4+0..3 then 64+q4+0..3), cross-group merge lex -> exact first-min.
__global__ __launch_bounds__(256, 6)
void fused_l1(const float* __restrict__ H, const float* __restrict__ M,
              const float* __restrict__ Hdec, const float* __restrict__ W,
              const float* __restrict__ X, const float* __restrict__ w_d,
              float* __restrict__ MT, float* __restrict__ pd,
              int* __restrict__ pi, float* __restrict__ pp,
              float* __restrict__ accum) {
    __shared__ __align__(16) float smem[6144];   // 24KB
    const int tid = threadIdx.x;

    if (blockIdx.x >= XG_BLOCKS) {
        // ------------------------------- NN tile -------------------------------
        // hT dbuf [2][16][64] = smem[0..2047]; mT dbuf [2][16][128] = smem[2048..6143]
        float* rd = smem;                    // [16][64] alias (after final bar)
        int*   ri = (int*)(smem + 1024);     // [16][64] alias

        const int nb    = blockIdx.x - XG_BLOCKS;
        const int ptile = nb >> 2;           // 128 pos-tiles (64 wide)
        const int ktile = nb & 3;            // 4 k-tiles (128 wide)
        const int pos0  = ptile << 6;
        const int b     = pos0 >> 10;
        const int t0    = pos0 & 1023;
        const int k0    = ktile << 7;
        const float* Hb = H + (b << 17) + t0;

        const int wv = tid >> 6;             // wave id 0..3 (uniform per wave)
        const int p4 = (tid & 15) << 2;      // compute pos quad (0..60)
        const int q4 = (tid >> 4) << 2;      // compute k quad   (0..60), split-k

        // lane-linear staging sources (LDS float off == tid*4 per region/pass)
        const float* hsrc = Hb + (size_t)(tid >> 4) * 1024 + ((tid & 15) << 2);
        const float* msrc = M + (size_t)(tid >> 5) * K_DIM + k0 + ((tid & 31) << 2);
        float* hdstw = smem + (wv << 8);          // + sel*1024
        float* mdstw = smem + 2048 + (wv << 8);   // + sel*2048 + pass*1024

        float acc[4][8];
#pragma unroll
        for (int i = 0; i < 4; ++i)
#pragma unroll
            for (int j = 0; j < 8; ++j) acc[i][j] = 0.f;

        // stage chunk ch (16 d rows starting at ch*16) into buffer sel
        auto stage = [&](int ch, int sel) {
            const size_t dd = (size_t)ch << 4;
            gll16(hsrc + (dd << 10), hdstw + (sel << 10));
            gll16(msrc + dd * K_DIM,             mdstw + (sel << 11));
            gll16(msrc + (dd + 8) * K_DIM,       mdstw + (sel << 11) + 1024);
        };

        stage(0, 0);                         // prologue (drained by 1st barrier)

        for (int ch = 0; ch < 8; ++ch) {
            __syncthreads();   // drains vmcnt -> buf[ch&1] ready for ALL waves
            if (ch < 7) stage(ch + 1, (ch + 1) & 1);   // async into other buf

            const float* hc = smem + ((ch & 1) << 10);
            const float* mc = smem + 2048 + ((ch & 1) << 11);
#pragma unroll 4
            for (int d = 0; d < 16; ++d) {
                const float4 ha = *(const float4*)(hc + (d << 6) + p4);
                const float4 m0 = *(const float4*)(mc + (d << 7) + q4);
                const float4 m1 = *(const float4*)(mc + (d << 7) + 64 + q4);
                const float hh[4] = {ha.x, ha.y, ha.z, ha.w};
                const float mm[8] = {m0.x, m0.y, m0.z, m0.w,
                                     m1.x, m1.y, m1.z, m1.w};
#pragma unroll
                for (int i = 0; i < 4; ++i)
#pragma unroll
                    for (int j = 0; j < 8; ++j) {
                        const float dv = hh[i] - mm[j];
                        asm("v_add_f32 %0, %0, abs(%1)"
                            : "+v"(acc[i][j]) : "v"(dv));
                    }
            }
        }

        __syncthreads();   // all reads of smem done before aliasing as rd/ri

        // per-thread argmin over its 8 ks (j ascending = k ascending; strict <)
#pragma unroll
        for (int i = 0; i < 4; ++i) {
            const int pl = p4 + i;           // local pos 0..63
            float bd = acc[i][0];
            int   bj = 0;
#pragma unroll
            for (int j = 1; j < 8; ++j)
                if (acc[i][j] < bd) { bd = acc[i][j]; bj = j; }
            const int bk = k0 + ((bj < 4) ? (q4 + bj) : (64 + q4 + bj - 4));
            rd[(tid >> 4) * 64 + pl] = bd;
            ri[(tid >> 4) * 64 + pl] = bk;
        }
        __syncthreads();

        // cross-thread merge: 16 k-groups, lexicographic (dist, k)
        if (tid < 64) {
            float bd = rd[tid];
            int   bi = ri[tid];
#pragma unroll
            for (int q = 1; q < 16; ++q) {
                const float d = rd[q * 64 + tid];
                const int   k = ri[q * 64 + tid];
                if (d < bd || (d == bd && k < bi)) { bd = d; bi = k; }
            }
            pd[ktile * N_POS + pos0 + tid] = bd;
            pi[ktile * N_POS + pos0 + tid] = bi;
        }
    } else {
        // --------------------- XHAT + E(LDS) + GREC partials -------------------
        float* El = smem;                    // [32][32]
        const int xb  = blockIdx.x;          // 0..255
        const int bt0 = xb << 5;

        // first 64 xg blocks transpose one 2-d x 512-k slab of M into MT
        if (xb < 64) {
            const int d0 = xb << 1;          // 2 d-rows per block, 512 k each
            const int d  = d0 + (tid >> 7);
            const int k  = (tid & 127) << 2;
#pragma unroll
            for (int j = 0; j < 4; ++j)
                MT[(size_t)(k + j) * D_DIM + d] = M[(size_t)d * K_DIM + k + j];
        }

        const int c  = tid & 31;
        const int rg = tid >> 5;
        const int r0 = bt0 + rg, r1 = r0 + 8, r2 = r0 + 16, r3 = r0 + 24;

        // W row c read straight from global: 32KB total, L1/L2-resident.
        const float* Wc = W + (size_t)c * F_DIM;

        float a0 = 0.f, a1 = 0.f, a2 = 0.f, a3 = 0.f;
#pragma unroll 4
        for (int f0 = 0; f0 < F_DIM; f0 += 4) {
            const float4 w4 = *(const float4*)(Wc + f0);
            const float4 h0 = *(const float4*)(Hdec + (size_t)r0 * F_DIM + f0);
            const float4 h1 = *(const float4*)(Hdec + (size_t)r1 * F_DIM + f0);
            const float4 h2 = *(const float4*)(Hdec + (size_t)r2 * F_DIM + f0);
            const float4 h3 = *(const float4*)(Hdec + (size_t)r3 * F_DIM + f0);
            a0 += h0.x * w4.x + h0.y * w4.y + h0.z * w4.z + h0.w * w4.w;
            a1 += h1.x * w4.x + h1.y * w4.y + h1.z * w4.z + h1.w * w4.w;
            a2 += h2.x * w4.x + h2.y * w4.y + h2.z * w4.z + h2.w * w4.w;
            a3 += h3.x * w4.x + h3.y * w4.y + h3.z * w4.z + h3.w * w4.w;
        }

        const float wd = w_d[c];
        const float e0 = a0 - X[(size_t)r0 * C_DIM + c];
        const float e1 = a1 - X[(size_t)r1 * C_DIM + c];
        const float e2 = a2 - X[(size_t)r2 * C_DIM + c];
        const float e3 = a3 - X[(size_t)r3 * C_DIM + c];
        El[(rg)      * 32 + c] = e0;
        El[(rg + 8)  * 32 + c] = e1;
        El[(rg + 16) * 32 + c] = e2;
        El[(rg + 24) * 32 + c] = e3;
        const float sse = e0 * e0 + e1 * e1 + e2 * e2 + e3 * e3;
        const float dp  = (a0 + a1 + a2 + a3) * wd;
        const float rA = block_reduce_256(sse);
        if (tid == 0) atomicAdd(accum + 0, rA);
        const float rB = block_reduce_256(dp);
        if (tid == 0) atomicAdd(accum + 1, rB);
        __syncthreads();   // El fully visible

        // grec: thread = f; E rows via LDS float4 broadcast; 2-deep prefetch.
        const int f = tid;
        const float* hp = Hdec + (size_t)bt0 * F_DIM + f;
        float gacc[C_DIM];
#pragma unroll
        for (int cc = 0; cc < C_DIM; ++cc) gacc[cc] = 0.f;
        float sf = 0.f;
        float hd0 = hp[0];
        float hd1 = hp[F_DIM];
#pragma unroll 1
        for (int i = 0; i < 30; ++i) {
            const float hdn = hp[(size_t)(i + 2) * F_DIM];
            sf += hd0;
#pragma unroll
            for (int c4 = 0; c4 < 8; ++c4) {
                const float4 e4 = *(const float4*)(El + i * 32 + c4 * 4);
                gacc[c4 * 4 + 0] += e4.x * hd0;
                gacc[c4 * 4 + 1] += e4.y * hd0;
                gacc[c4 * 4 + 2] += e4.z * hd0;
                gacc[c4 * 4 + 3] += e4.w * hd0;
            }
            hd0 = hd1; hd1 = hdn;
        }
#pragma unroll
        for (int i = 30; i < 32; ++i) {
            sf += hd0;
#pragma unroll
            for (int c4 = 0; c4 < 8; ++c4) {
                const float4 e4 = *(const float4*)(El + i * 32 + c4 * 4);
                gacc[c4 * 4 + 0] += e4.x * hd0;
                gacc[c4 * 4 + 1] += e4.y * hd0;
                gacc[c4 * 4 + 2] += e4.z * hd0;
                gacc[c4 * 4 + 3] += e4.w * hd0;
            }
            hd0 = hd1;
        }
        float* o = pp + (size_t)xb * GREC_COLS;
#pragma unroll
        for (int cc = 0; cc < C_DIM; ++cc) o[cc * F_DIM + f] = gacc[cc];
        o[8192 + f] = sf;
    }
}

// ============ L2: merge+SSE (0..255), norm reduce (256..387), assemble ======
__global__ __launch_bounds__(256)
void fused_l2(const float* __restrict__ H, const float* __restrict__ MT,
              const float* __restrict__ pd, const int* __restrict__ pi,
              const float* __restrict__ pp, const float* __restrict__ w_d,
              float* __restrict__ accum, float* __restrict__ out) {
    const int tid = threadIdx.x;
    if (blockIdx.x < 256) {
        // ---------------- chunk-merge + memory-loss SSE ----------------
        const int bx = blockIdx.x & 31;      // pos-block
        const int by = blockIdx.x >> 5;      // d-slice 0..7
        const int pos = bx * 256 + tid;
        const int b = pos >> 10;
        const int t = pos & 1023;

        // H loads are independent of the merge -> issue them FIRST (MLP)
        const int d0 = by * 16;
        const float* Hb = H + (b << 17) + t + (d0 << 10);
        float hv[16];
#pragma unroll
        for (int j = 0; j < 16; ++j) hv[j] = Hb[j << 10];

        float bd = INFINITY;
        int   bi = 0x7fffffff;
#pragma unroll
        for (int p = 0; p < NKT; ++p) {
            const float d = pd[p * N_POS + pos];
            const int   k = pi[p * N_POS + pos];
            if (d < bd || (d == bd && k < bi)) { bd = d; bi = k; }
        }

        const float* z  = MT + (size_t)bi * D_DIM + d0;
        const float4 z0 = *(const float4*)(z);
        const float4 z1 = *(const float4*)(z + 4);
        const float4 z2 = *(const float4*)(z + 8);
        const float4 z3 = *(const float4*)(z + 12);
        float s0 = 0.f, s1 = 0.f, s2 = 0.f, s3 = 0.f;
        float e;
        e = hv[0]  - z0.x; s0 += e * e;
        e = hv[1]  - z0.y; s1 += e * e;
        e = hv[2]  - z0.z; s2 += e * e;
        e = hv[3]  - z0.w; s3 += e * e;
        e = hv[4]  - z1.x; s0 += e * e;
        e = hv[5]  - z1.y; s1 += e * e;
        e = hv[6]  - z1.z; s2 += e * e;
        e = hv[7]  - z1.w; s3 += e * e;
        e = hv[8]  - z2.x; s0 += e * e;
        e = hv[9]  - z2.y; s1 += e * e;
        e = hv[10] - z2.z; s2 += e * e;
        e = hv[11] - z2.w; s3 += e * e;
        e = hv[12] - z3.x; s0 += e * e;
        e = hv[13] - z3.y; s1 += e * e;
        e = hv[14] - z3.z; s2 += e * e;
        e = hv[15] - z3.w; s3 += e * e;
        const float r = block_reduce_256((s0 + s1) + (s2 + s3));
        if (tid == 0) atomicAdd(accum + 2, r);
    } else {
        // ---------------- norm reductions over pp ----------------
        const int g = blockIdx.x - 256;                // 0..131
        const int col = (g < 128) ? (g * 64 + (tid & 63))
                                  : (8192 + (g - 128) * 64 + (tid & 63));
        const int pc  = tid >> 6;                      // 0..3
        const float* base = pp + (size_t)(pc * 64) * GREC_COLS + col;
        float s = 0.f;
#pragma unroll 8
        for (int p = 0; p < 64; ++p) s += base[(size_t)p * GREC_COLS];
        __shared__ float red[4][64];
        red[pc][tid & 63] = s;
        __syncthreads();
        if (tid < 64) {
            const float tot = red[0][tid] + red[1][tid] +
                              red[2][tid] + red[3][tid];
            float v = tot * tot;
#pragma unroll
            for (int off = 32; off > 0; off >>= 1) v += __shfl_down(v, off);
            if (tid == 0)
                atomicAdd(accum + ((g >= 128) ? 4 : 3), v);
        }
    }

    // ---- last block to finish assembles the scalar ----
    __shared__ int is_last;
    if (tid == 0) {
        __threadfence();
        unsigned int* cnt = (unsigned int*)(accum + 5);
        is_last = (atomicAdd(cnt, 1u) == L2_BLOCKS - 1);
    }
    __syncthreads();
    if (is_last && tid < 64) {
        float wd2 = (tid < C_DIM) ? w_d[tid] * w_d[tid] : 0.f;
#pragma unroll
        for (int off = 32; off > 0; off >>= 1) wd2 += __shfl_down(wd2, off);
        if (tid == 0) {
            __threadfence();
            const float sse_rec = atomicAdd(accum + 0, 0.f);
            const float dsum    = atomicAdd(accum + 1, 0.f);
            const float sse_mem = atomicAdd(accum + 2, 0.f);
            const float g2      = atomicAdd(accum + 3, 0.f);
            const float s2      = atomicAdd(accum + 4, 0.f);
            const float loss_rec = sse_rec / 262144.f;         // /(B*T*C)
            const float loss_d   = -dsum / 8192.f;             // -mean over B*T
            const float loss_m   = 2.f * sse_mem / 1048576.f;  // 2*SSE/(B*D*T)
            const float ngrec    = (2.f / 262144.f) * sqrtf(g2);
            const float ngd      = sqrtf(wd2 * s2) / 8192.f;
            const float lmbda    = ngrec / (ngd + 1e-6f);
            out[0] = loss_rec + loss_m + lmbda * loss_d;       // ALPHA = 1
        }
    }
}

// ---------------------------------------------------------------- launcher
extern "C" void kernel_launch(void* const* d_in, const int* in_sizes, int n_in,
                              void* d_out, int out_size, void* d_ws, size_t ws_size,
                              hipStream_t stream) {
    const float* X    = (const float*)d_in[0];   // [8,1024,32]
    const float* H    = (const float*)d_in[1];   // [8,128,1024]
    const float* M    = (const float*)d_in[2];   // [128,512]
    const float* Hdec = (const float*)d_in[3];   // [8,1024,256]
    const float* W    = (const float*)d_in[4];   // [32,256]
    const float* w_d  = (const float*)d_in[5];   // [32]

    float* ws    = (float*)d_ws;
    float* MT    = ws;                      // 65536 floats
    float* accum = ws + 65536;              // 16 (counter at [5])
    float* pd    = ws + 65552;              // 4*8192 = 32768
    int*   pi    = (int*)(ws + 98320);      // 32768
    float* pp    = ws + 131088;             // 256*8448 = 2162688  (~9.2 MB total)

    hipMemsetAsync(accum, 0, 16 * sizeof(float), stream);
    fused_l1<<<GRID_L1,   256, 0, stream>>>(H, M, Hdec, W, X, w_d,
                                            MT, pd, pi, pp, accum);
    fused_l2<<<L2_BLOCKS, 256, 0, stream>>>(H, MT, pd, pi, pp, w_d,
                                            accum, (float*)d_out);
}